// Round 5
// baseline (8532.071 us; speedup 1.0000x reference)
//
#include <hip/hip_runtime.h>

// ---------------------------------------------------------------------------
// PolicyNetRSNNPB forward, MI355X/gfx950.  Round 14: flag-gated exchange.
// r13: wall 5147, k_rec 4680 us = 9.1 us/step = 2.6 MAC + 6.4 exchange.
// r12->r13 delta (-0.54 us/step for -1 VALU/MAC) validates the MAC model, so
// the exchange is the wall. vs r10 (7.2 us/step, 1 tagged word/thread poll),
// r13 spins on 8 LLC words/thread (16 lines/wave/iter x 2048 waves) -> poll
// flood contends in LLC (FETCH 68->108 MB) and burns issue slots.
// THIS ROUND (k_rec only): per-(producer,step) FLAG array (no-reuse, 256 KB).
//   Producer: wave0 stores 64 tagged ring words (unchanged), then lane0
//   RELEASE-stores flag[step][R][cb] = i+1 (one ordered store/block-step).
//   Consumer: spins on ONE flag load/lane (8 unique words = 1 line/wave);
//   then does the tagged 8-word read ONCE (tags still validate -> same
//   correctness basis as r13; premature flag only causes brief tag-spin;
//   no fences needed; poison/zero never matches since expct>=1).
// MAC, epilogue, barriers, ring format, all other kernels: byte-identical.
// Arithmetic FROZEN (numpy-fp32 emulation), BIT-EXACT to r10..r13.
// ---------------------------------------------------------------------------

typedef unsigned int       u32;
typedef unsigned short     u16;
typedef unsigned long long u64;
typedef unsigned char      u8;

#define TSTEPS 512
#define HIDDEN 512

// workspace layout (bytes).
//   [0,64Mi)   XW transposed (dead after k_rec; c3 [0,32Mi) + Mem [32Mi,64Mi))
//   [64,80Mi)  ring32 (no-reuse tagged spike ring, k_rec only)
//   [80Mi+..)  flags  (no-reuse producer flags, 256 KB)
//   [96,100Mi) spkb8 (ff spike history, bytes)
//   [104Mi..)  WT, WinT (unchanged)
#define XW_OFF    0ull
#define C3_OFF    0ull
#define MEM_OFF   33554432ull
#define RINGN_OFF 67108864ull
#define FLAG_OFF  83886080ull
#define SPKB_OFF  100663296ull
#define WT_OFF    109051904ull
#define WINT_OFF  109314048ull
#define WS_NEED   (134742016ull + 4096ull)

// ---------------------------------------------------------------------------
__global__ __launch_bounds__(256) void k_prepT(
    const float* __restrict__ Win,
    const float* __restrict__ Wmu, const float* __restrict__ Wlv,
    float* __restrict__ WinT, float* __restrict__ WT)
{
  const int idx = blockIdx.x * 256 + threadIdx.x;
  if (idx < 65536) {
    const int k = idx >> 9, j = idx & 511;
    WinT[idx] = Win[j * 128 + k];
  } else {
    const int i2 = idx - 65536;
    const int k = i2 >> 7, j = i2 & 127;
    WT[i2] = (j < 64) ? Wmu[j * 512 + k] : Wlv[(j - 64) * 512 + k];
  }
}

// ---------------------------------------------------------------------------
// k_xw: unchanged GEMM, TRANSPOSED store: XWT[(t2*512 + j)*128 + n].
// ---------------------------------------------------------------------------
__global__ __launch_bounds__(256) void k_xw(
    const float* __restrict__ state, const float* __restrict__ target,
    const float* __restrict__ WinT, const float* __restrict__ b_in,
    float* __restrict__ XWT)
{
  __shared__ float xs[16][129];
  const int tid  = threadIdx.x;
  const int row0 = blockIdx.x * 16;

  for (int e = tid; e < 2048; e += 256) {
    int r = e >> 7, k = e & 127;
    xs[r][k] = (k < 64) ? state[(row0 + r) * 64 + k]
                        : target[(row0 + r) * 64 + k - 64];
  }
  __syncthreads();

  const int t2 = row0 >> 7;
  const int n0 = row0 & 127;

#pragma unroll
  for (int jh = 0; jh < 2; ++jh) {
    const int j = jh * 256 + tid;
    float acc[16];
#pragma unroll
    for (int r = 0; r < 16; ++r) acc[r] = 0.0f;
    for (int k = 0; k < 128; ++k) {
      const float wv = WinT[k * 512 + j];
#pragma unroll
      for (int r = 0; r < 16; ++r)
        acc[r] = __builtin_fmaf(xs[r][k], wv, acc[r]);
    }
    const float b = b_in[j];
    float* dst = XWT + ((u64)t2 * 512 + j) * 128 + n0;
#pragma unroll
    for (int r4 = 0; r4 < 4; ++r4) {
      float4 o;
      o.x = __fadd_rn(acc[r4 * 4 + 0], b);
      o.y = __fadd_rn(acc[r4 * 4 + 1], b);
      o.z = __fadd_rn(acc[r4 * 4 + 2], b);
      o.w = __fadd_rn(acc[r4 * 4 + 3], b);
      *(float4*)(dst + r4 * 4) = o;
    }
  }
}

// ---------------------------------------------------------------------------
// k_rec: grid 256 x 512 threads (8 waves, 2/SIMD, forced 1 block/CU via LDS).
// blockIdx < 128: REC; >= 128: FF. Block (role, cb, R): wave w -> hidden unit
// jj = 8cb+w (wave-uniform, scalarized), lane n -> row gn = R*64+n.
// Exchange: flag-gated one-shot tagged reads (this round's change).
// MAC: v_bfe_i32 + v_and_b32 + v_add_f32 (3 VALU), ascending k, 384-split.
// ---------------------------------------------------------------------------
__global__ __launch_bounds__(512, 2) void k_rec(
    const float* __restrict__ XWT,
    const float* __restrict__ Wrec, const float* __restrict__ Wff,
    const float* __restrict__ alpha_rec, const float* __restrict__ beta_rec,
    const float* __restrict__ b_rec,
    const float* __restrict__ b_ff, const float* __restrict__ alpha_ff,
    const float* __restrict__ beta_ff,
    u32* __restrict__ ring32, u32* __restrict__ flags,
    u8* __restrict__ spkb8)
{
  __shared__ __align__(16) u8 MB[64][80];   // [row][c8 byte], pad 80 (5120 B)
  __shared__ __align__(8)  u8 SP[64][8];    // [row][wave] spike bytes (512 B)
  __shared__ float padlds[19328];           // 77312 B -> total 82944 B:
                                            // forces exactly 1 block/CU.

  const int tid  = threadIdx.x;
  const int w    = tid >> 6;          // wave 0..7  -> j-offset
  const int n    = tid & 63;          // lane       -> row within rowgroup
  const int bb   = blockIdx.x & 127;
  const bool isFF = (blockIdx.x >= 128);
  const int cb   = bb >> 1;           // j-octet 0..63
  const int R    = bb & 1;            // rowgroup
  const int wrf  = __builtin_amdgcn_readfirstlane(w);
  const int jj   = cb * 8 + wrf;      // hidden unit (scalar/SGPR)
  const int gn   = R * 64 + n;        // global batch row

  // wave-uniform weight row base (scalar pointer -> scalar/uniform loads)
  const float* __restrict__ Wrow = (isFF ? Wff : Wrec) + (u64)jj * 512;

  const float coA = isFF ? alpha_ff[jj] : alpha_rec[jj];
  const float coB = isFF ? beta_ff[jj]  : beta_rec[jj];
  const float coC = isFF ? b_ff[jj]     : b_rec[jj];

  // keep the co-residency pad alive (never read back; one-time cost)
  ((volatile float*)padlds)[tid] = coC;

  float syn = 0.f, mem = 0.f, spk = 0.f, xw = 0.f;

#pragma unroll 1
  for (int i = 0; i < TSTEPS; ++i) {
    if (!isFF && !(i & 1))
      xw = XWT[((u64)(i >> 1) * 512 + jj) * 128 + gn];

    const int slot  = isFF ? i : (i - 1);
    const u32 expct = isFF ? (u32)(i + 1) : (u32)i;

    if (expct) {
      // -------- flag gate: ONE load/lane over the wave's 8 producers ------
      const u32* fl = flags + ((u64)slot * 2 + R) * 64 + 8 * w + (n & 7);
      u32 fv = __hip_atomic_load(fl, __ATOMIC_RELAXED, __HIP_MEMORY_SCOPE_AGENT);
      while (!__all(fv == expct)) {
        __builtin_amdgcn_s_sleep(1);
        fv = __hip_atomic_load(fl, __ATOMIC_RELAXED, __HIP_MEMORY_SCOPE_AGENT);
      }
      // -------- one-shot tagged reads (tags validate; ~no spin here) ------
      const u32* src = ring32 + ((u64)slot * 64 + 8 * w) * 128 + gn;
      u32 vv[8];
      for (;;) {
        u32 bad = 0;
#pragma unroll
        for (int s = 0; s < 8; ++s) {
          vv[s] = __hip_atomic_load(src + s * 128, __ATOMIC_RELAXED,
                                    __HIP_MEMORY_SCOPE_AGENT);
          bad |= (vv[s] >> 8) ^ expct;
        }
        if (__all(bad == 0)) break;
        __builtin_amdgcn_s_sleep(1);
      }
      u64 mb = 0;
#pragma unroll
      for (int s = 0; s < 8; ++s) mb |= (u64)(vv[s] & 0xFFu) << (8 * s);
      *(u64*)&MB[n][8 * w] = mb;
    }
    __syncthreads();  // bar1: MB complete (prev-iter MAC reads fenced by bar2)

    float SA = 0.f;
    if (expct) {
      // own row's 512 spike bits: 64 bytes -> 16 VGPRs
      const uint4* bq = (const uint4*)&MB[n][0];
      const uint4 q0 = bq[0], q1 = bq[1], q2 = bq[2], q3 = bq[3];
      const u32 bw[16] = { q0.x, q0.y, q0.z, q0.w, q1.x, q1.y, q1.z, q1.w,
                           q2.x, q2.y, q2.z, q2.w, q3.x, q3.y, q3.z, q3.w };
      float aA = 0.f, aB = 0.f;
      // BLAS-faithful: ascending k, chunk split at 384, merged by one fadd.
      // Per k: bfe_i32 (0/-1 mask) + and with uniform weight + fadd.
#pragma unroll
      for (int kb = 0; kb < 12; ++kb) {
        const u32 word = bw[kb];
#pragma unroll
        for (int t = 0; t < 32; ++t) {
          const int m = (int)(word << (31 - t)) >> 31;            // 0 / -1
          const float ws =
              __int_as_float(m & __float_as_int(Wrow[kb * 32 + t]));
          aA = __fadd_rn(aA, ws);
        }
      }
#pragma unroll
      for (int kb = 12; kb < 16; ++kb) {
        const u32 word = bw[kb];
#pragma unroll
        for (int t = 0; t < 32; ++t) {
          const int m = (int)(word << (31 - t)) >> 31;
          const float ws =
              __int_as_float(m & __float_as_int(Wrow[kb * 32 + t]));
          aB = __fadd_rn(aB, ws);
        }
      }
      SA = __fadd_rn(aA, aB);
    }

    // epilogue (single-rounded, identical op sequence to r10..r13)
    const float cur = isFF ? __fadd_rn(SA, coC)
                           : __fadd_rn(__fadd_rn(xw, SA), coC);
    syn = __fadd_rn(__fmul_rn(coA, syn), cur);
    mem = __fsub_rn(__fadd_rn(__fmul_rn(coB, mem), syn), spk);
    spk = (mem > 1.0f) ? 1.0f : 0.0f;
    SP[n][w] = (u8)(spk != 0.f);

    __syncthreads();  // bar2: SP complete; also fences MB reuse next iter

    if (w == 0) {
      const u64 sv  = *(const u64*)&SP[n][0];
      const u32 lo4 = ((u32)sv         * 0x01020408u) >> 24;  // bits w=0..3
      const u32 hi4 = ((u32)(sv >> 32) * 0x01020408u) >> 24;  // bits w=4..7
      const u32 mask = lo4 | (hi4 << 4);
      if (!isFF) {
        __hip_atomic_store(ring32 + ((u64)i * 64 + cb) * 128 + gn,
                           ((u32)(i + 1) << 8) | mask,
                           __ATOMIC_RELAXED, __HIP_MEMORY_SCOPE_AGENT);
        if (n == 0)
          __hip_atomic_store(flags + ((u64)i * 2 + R) * 64 + cb, (u32)(i + 1),
                             __ATOMIC_RELEASE, __HIP_MEMORY_SCOPE_AGENT);
      } else {
        spkb8[((u64)i * 64 + cb) * 128 + gn] = (u8)mask;
      }
    }
  }
}

// ---------------------------------------------------------------------------
// k_c3: spk_f history (bytes, c8-major) @ W_mu/W_lv readout, + bias.
// ---------------------------------------------------------------------------
__global__ __launch_bounds__(256) void k_c3(
    const u8* __restrict__ spkb8, const float* __restrict__ WT,
    const float* __restrict__ bmu, const float* __restrict__ blv,
    float* __restrict__ c3)
{
  __shared__ __align__(8) u8 Bc[64][40];  // [c8][n-local 32, pad 40]
  const int tid   = threadIdx.x;
  const int rows0 = blockIdx.x * 32;
  const int t     = rows0 >> 7;
  const int n0    = rows0 & 127;

  {
    const int c8 = tid >> 2, g = tid & 3;
    const u64 vv = *(const u64*)(spkb8 + ((u64)t * 64 + c8) * 128 + n0 + 8 * g);
    *(u64*)&Bc[c8][8 * g] = vv;
  }
  __syncthreads();

  const int j  = tid & 127;
  const int rh = tid >> 7;
  const float bias = (j < 64) ? bmu[j] : blv[j - 64];

  float accA[16], accB[16];
#pragma unroll
  for (int r = 0; r < 16; ++r) { accA[r] = 0.f; accB[r] = 0.f; }

  for (int m = 0; m < 48; ++m) {   // k = 8m+kk < 384
    u32 w32[4];
#pragma unroll
    for (int q = 0; q < 4; ++q) w32[q] = *(const u32*)&Bc[m][rh * 16 + 4 * q];
    const float* wpp = WT + (m * 8) * 128 + j;
#pragma unroll
    for (int kk = 0; kk < 8; ++kk) {
      const float wvv = wpp[kk * 128];
#pragma unroll
      for (int r = 0; r < 16; ++r) {
        const float b = (float)((w32[r >> 2] >> (((r & 3) << 3) + kk)) & 1u);
        accA[r] = __builtin_fmaf(b, wvv, accA[r]);
      }
    }
  }
  for (int m = 48; m < 64; ++m) {  // k >= 384
    u32 w32[4];
#pragma unroll
    for (int q = 0; q < 4; ++q) w32[q] = *(const u32*)&Bc[m][rh * 16 + 4 * q];
    const float* wpp = WT + (m * 8) * 128 + j;
#pragma unroll
    for (int kk = 0; kk < 8; ++kk) {
      const float wvv = wpp[kk * 128];
#pragma unroll
      for (int r = 0; r < 16; ++r) {
        const float b = (float)((w32[r >> 2] >> (((r & 3) << 3) + kk)) & 1u);
        accB[r] = __builtin_fmaf(b, wvv, accB[r]);
      }
    }
  }

#pragma unroll
  for (int r = 0; r < 16; ++r)
    c3[(u64)(rows0 + rh * 16 + r) * 128 + j] =
        __fadd_rn(__fadd_rn(accA[r], accB[r]), bias);
}

// ---------------------------------------------------------------------------
__global__ __launch_bounds__(256) void k_scan(
    const float* __restrict__ c3,
    const float* __restrict__ beta_mu, const float* __restrict__ beta_lv,
    float* __restrict__ Mem)
{
  const int tid = blockIdx.x * 256 + threadIdx.x;
  const int n = tid >> 7, ap = tid & 127;
  const float beta = (ap < 64) ? beta_mu[ap] : beta_lv[ap - 64];
  const float* src = c3 + n * 128 + ap;
  float* dst = Mem + n * 128 + ap;
  float mem = 0.0f;
  for (int t = 0; t < 512; ++t) {
    mem = __fadd_rn(__fmul_rn(beta, mem), src[(u64)t * 16384]);
    dst[(u64)t * 16384] = mem;
  }
}

// ---------------------------------------------------------------------------
__global__ __launch_bounds__(256) void k_out(
    const float* __restrict__ Mem,
    const float* __restrict__ Wmu_out, const float* __restrict__ Wlv_out,
    float* __restrict__ out)
{
  const int tid = blockIdx.x * 256 + threadIdx.x;
  const int a = tid & 7;
  const int n = (tid >> 3) & 127;
  const int t = (tid >> 10) & 255;
  const int kind = tid >> 18;
  const float* wv = ((kind == 0) ? Wmu_out : Wlv_out) + a * 64;
  const float* s0 = Mem + ((u64)(2 * t) * 128 + n) * 128 + kind * 64;
  const float* s1 = Mem + ((u64)(2 * t + 1) * 128 + n) * 128 + kind * 64;
  float mu0 = 0.0f, mu1 = 0.0f;
#pragma unroll 8
  for (int q = 0; q < 64; ++q) mu0 = __builtin_fmaf(s0[q], wv[q], mu0);
#pragma unroll 8
  for (int q = 0; q < 64; ++q) mu1 = __builtin_fmaf(s1[q], wv[q], mu1);
  out[tid] = __fmul_rn(__fadd_rn(mu0, mu1), 0.5f);
}

// ---------------------------------------------------------------------------
extern "C" void kernel_launch(void* const* d_in, const int* in_sizes, int n_in,
                              void* d_out, int out_size, void* d_ws, size_t ws_size,
                              hipStream_t stream) {
  (void)in_sizes; (void)n_in; (void)out_size;
  if (ws_size < WS_NEED) return;

  const float* state     = (const float*)d_in[0];
  const float* target    = (const float*)d_in[1];
  const float* W_rec_in  = (const float*)d_in[2];
  const float* b_rec_in  = (const float*)d_in[3];
  const float* W_rec     = (const float*)d_in[4];
  const float* b_rec     = (const float*)d_in[5];
  const float* alpha_rec = (const float*)d_in[6];
  const float* beta_rec  = (const float*)d_in[7];
  const float* W_ff_in   = (const float*)d_in[8];
  const float* b_ff_in   = (const float*)d_in[9];
  const float* alpha_ff  = (const float*)d_in[10];
  const float* beta_ff   = (const float*)d_in[11];
  const float* W_mu_in   = (const float*)d_in[12];
  const float* b_mu_in   = (const float*)d_in[13];
  const float* beta_mu   = (const float*)d_in[14];
  const float* W_mu_out  = (const float*)d_in[15];
  const float* W_lv_in   = (const float*)d_in[16];
  const float* b_lv_in   = (const float*)d_in[17];
  const float* beta_lv   = (const float*)d_in[18];
  const float* W_lv_out  = (const float*)d_in[19];

  char* ws = (char*)d_ws;
  float* XWT   = (float*)(ws + XW_OFF);
  float* c3    = (float*)(ws + C3_OFF);
  float* Mem   = (float*)(ws + MEM_OFF);
  u32*   ring32= (u32*)  (ws + RINGN_OFF);
  u32*   flags = (u32*)  (ws + FLAG_OFF);
  u8*    spkb8 = (u8*)   (ws + SPKB_OFF);
  float* WT    = (float*)(ws + WT_OFF);
  float* WinT  = (float*)(ws + WINT_OFF);

  hipLaunchKernelGGL(k_prepT, dim3(512), dim3(256), 0, stream,
                     W_rec_in, W_mu_in, W_lv_in, WinT, WT);
  hipLaunchKernelGGL(k_xw, dim3(2048), dim3(256), 0, stream,
                     state, target, WinT, b_rec_in, XWT);
  hipLaunchKernelGGL(k_rec, dim3(256), dim3(512), 0, stream,
                     XWT, W_rec, W_ff_in,
                     alpha_rec, beta_rec, b_rec,
                     b_ff_in, alpha_ff, beta_ff, ring32, flags, spkb8);
  hipLaunchKernelGGL(k_c3, dim3(2048), dim3(256), 0, stream,
                     spkb8, WT, b_mu_in, b_lv_in, c3);
  hipLaunchKernelGGL(k_scan, dim3(64), dim3(256), 0, stream,
                     c3, beta_mu, beta_lv, Mem);
  hipLaunchKernelGGL(k_out, dim3(2048), dim3(256), 0, stream,
                     Mem, W_mu_out, W_lv_out, (float*)d_out);
}

// Round 6
// 5152.931 us; speedup vs baseline: 1.6558x; 1.6558x over previous
//
#include <hip/hip_runtime.h>

// ---------------------------------------------------------------------------
// PolicyNetRSNNPB forward, MI355X/gfx950.  Round 15: de-flood the poll spin.
// r14 (flag gate) regressed 4680->8054 us: one flag line per (step,R) polled
// by ~1024 waves -> LLC hot-line serialization + an extra dependent hop
// (store-drain -> flag -> observe -> data read). Lesson: reduce poll traffic
// WITHOUT adding serial hops or concentrating on single lines.
// r13's 6.4 us/step exchange is diagnosed as poll-flood feedback: ~190
// waiting blocks x 512 threads x 8 agent-scope LLC loads per ~100cy round
// contend with the critical ring stores, delaying the stragglers everyone
// waits on. THIS ROUND (k_rec poll section only; everything else = r13):
//   fast path: round 1 = full 8-word tagged read (data stays in regs, no
//              added latency when producers are ahead);
//   light spin: on failure, poll ONE word per lane (octet 8w; 4 distinct
//              lines per wave, different lines across waves) with s_sleep(2)
//              backoff -> ~8x less LLC poll traffic, no hot line;
//   verify:    full 8-word tagged rounds (usually 1; producers are near-
//              synchronous) with backoff.
// Correctness unchanged vs r13: same tags (expct>=1, zero/poison never
// matches), same no-reuse ring, spin-until-match, no ordering assumptions.
// Arithmetic FROZEN (numpy-fp32 emulation), BIT-EXACT to r10..r14.
// ---------------------------------------------------------------------------

typedef unsigned int       u32;
typedef unsigned short     u16;
typedef unsigned long long u64;
typedef unsigned char      u8;

#define TSTEPS 512
#define HIDDEN 512

// workspace layout (bytes).
//   [0,64Mi)   XW transposed (dead after k_rec; c3 [0,32Mi) + Mem [32Mi,64Mi))
//   [64,80Mi)  ring32 (no-reuse tagged spike ring, k_rec only)
//   [96,100Mi) spkb8 (ff spike history, bytes)
//   [104Mi..)  WT, WinT (unchanged)
#define XW_OFF    0ull
#define C3_OFF    0ull
#define MEM_OFF   33554432ull
#define RINGN_OFF 67108864ull
#define SPKB_OFF  100663296ull
#define WT_OFF    109051904ull
#define WINT_OFF  109314048ull
#define WS_NEED   (134742016ull + 4096ull)

// ---------------------------------------------------------------------------
__global__ __launch_bounds__(256) void k_prepT(
    const float* __restrict__ Win,
    const float* __restrict__ Wmu, const float* __restrict__ Wlv,
    float* __restrict__ WinT, float* __restrict__ WT)
{
  const int idx = blockIdx.x * 256 + threadIdx.x;
  if (idx < 65536) {
    const int k = idx >> 9, j = idx & 511;
    WinT[idx] = Win[j * 128 + k];
  } else {
    const int i2 = idx - 65536;
    const int k = i2 >> 7, j = i2 & 127;
    WT[i2] = (j < 64) ? Wmu[j * 512 + k] : Wlv[(j - 64) * 512 + k];
  }
}

// ---------------------------------------------------------------------------
// k_xw: unchanged GEMM, TRANSPOSED store: XWT[(t2*512 + j)*128 + n].
// ---------------------------------------------------------------------------
__global__ __launch_bounds__(256) void k_xw(
    const float* __restrict__ state, const float* __restrict__ target,
    const float* __restrict__ WinT, const float* __restrict__ b_in,
    float* __restrict__ XWT)
{
  __shared__ float xs[16][129];
  const int tid  = threadIdx.x;
  const int row0 = blockIdx.x * 16;

  for (int e = tid; e < 2048; e += 256) {
    int r = e >> 7, k = e & 127;
    xs[r][k] = (k < 64) ? state[(row0 + r) * 64 + k]
                        : target[(row0 + r) * 64 + k - 64];
  }
  __syncthreads();

  const int t2 = row0 >> 7;
  const int n0 = row0 & 127;

#pragma unroll
  for (int jh = 0; jh < 2; ++jh) {
    const int j = jh * 256 + tid;
    float acc[16];
#pragma unroll
    for (int r = 0; r < 16; ++r) acc[r] = 0.0f;
    for (int k = 0; k < 128; ++k) {
      const float wv = WinT[k * 512 + j];
#pragma unroll
      for (int r = 0; r < 16; ++r)
        acc[r] = __builtin_fmaf(xs[r][k], wv, acc[r]);
    }
    const float b = b_in[j];
    float* dst = XWT + ((u64)t2 * 512 + j) * 128 + n0;
#pragma unroll
    for (int r4 = 0; r4 < 4; ++r4) {
      float4 o;
      o.x = __fadd_rn(acc[r4 * 4 + 0], b);
      o.y = __fadd_rn(acc[r4 * 4 + 1], b);
      o.z = __fadd_rn(acc[r4 * 4 + 2], b);
      o.w = __fadd_rn(acc[r4 * 4 + 3], b);
      *(float4*)(dst + r4 * 4) = o;
    }
  }
}

// ---------------------------------------------------------------------------
// k_rec: grid 256 x 512 threads (8 waves, 2/SIMD, forced 1 block/CU via LDS).
// blockIdx < 128: REC; >= 128: FF. Block (role, cb, R): wave w -> hidden unit
// jj = 8cb+w (wave-uniform, scalarized), lane n -> row gn = R*64+n.
// Exchange: direct tagged polls, fast-path/light-spin/verify (this round).
// MAC: v_bfe_i32 + v_and_b32 + v_add_f32 (3 VALU), ascending k, 384-split.
// ---------------------------------------------------------------------------
__global__ __launch_bounds__(512, 2) void k_rec(
    const float* __restrict__ XWT,
    const float* __restrict__ Wrec, const float* __restrict__ Wff,
    const float* __restrict__ alpha_rec, const float* __restrict__ beta_rec,
    const float* __restrict__ b_rec,
    const float* __restrict__ b_ff, const float* __restrict__ alpha_ff,
    const float* __restrict__ beta_ff,
    u32* __restrict__ ring32, u8* __restrict__ spkb8)
{
  __shared__ __align__(16) u8 MB[64][80];   // [row][c8 byte], pad 80 (5120 B)
  __shared__ __align__(8)  u8 SP[64][8];    // [row][wave] spike bytes (512 B)
  __shared__ float padlds[19328];           // 77312 B -> total 82944 B:
                                            // forces exactly 1 block/CU.

  const int tid  = threadIdx.x;
  const int w    = tid >> 6;          // wave 0..7  -> j-offset
  const int n    = tid & 63;          // lane       -> row within rowgroup
  const int bb   = blockIdx.x & 127;
  const bool isFF = (blockIdx.x >= 128);
  const int cb   = bb >> 1;           // j-octet 0..63
  const int R    = bb & 1;            // rowgroup
  const int wrf  = __builtin_amdgcn_readfirstlane(w);
  const int jj   = cb * 8 + wrf;      // hidden unit (scalar/SGPR)
  const int gn   = R * 64 + n;        // global batch row

  // wave-uniform weight row base (scalar pointer -> scalar/uniform loads)
  const float* __restrict__ Wrow = (isFF ? Wff : Wrec) + (u64)jj * 512;

  const float coA = isFF ? alpha_ff[jj] : alpha_rec[jj];
  const float coB = isFF ? beta_ff[jj]  : beta_rec[jj];
  const float coC = isFF ? b_ff[jj]     : b_rec[jj];

  // keep the co-residency pad alive (never read back; one-time cost)
  ((volatile float*)padlds)[tid] = coC;

  float syn = 0.f, mem = 0.f, spk = 0.f, xw = 0.f;

#pragma unroll 1
  for (int i = 0; i < TSTEPS; ++i) {
    if (!isFF && !(i & 1))
      xw = XWT[((u64)(i >> 1) * 512 + jj) * 128 + gn];

    const int slot  = isFF ? i : (i - 1);
    const u32 expct = isFF ? (u32)(i + 1) : (u32)i;

    if (expct) {
      const u32* src = ring32 + ((u64)slot * 64 + 8 * w) * 128 + gn;
      u32 vv[8];
      // ---- fast path: one full tagged round (data stays in registers) ----
      u32 bad = 0;
#pragma unroll
      for (int s = 0; s < 8; ++s) {
        vv[s] = __hip_atomic_load(src + s * 128, __ATOMIC_RELAXED,
                                  __HIP_MEMORY_SCOPE_AGENT);
        bad |= (vv[s] >> 8) ^ expct;
      }
      if (!__all(bad == 0)) {
        // ---- light spin: 1 word/lane (4 lines/wave), sleep backoff ----
        u32 v0 = vv[0];
        while (!__all((v0 >> 8) == expct)) {
          __builtin_amdgcn_s_sleep(2);
          v0 = __hip_atomic_load(src, __ATOMIC_RELAXED,
                                 __HIP_MEMORY_SCOPE_AGENT);
        }
        // ---- verify: full tagged rounds (usually 1) ----
        for (;;) {
          bad = 0;
#pragma unroll
          for (int s = 0; s < 8; ++s) {
            vv[s] = __hip_atomic_load(src + s * 128, __ATOMIC_RELAXED,
                                      __HIP_MEMORY_SCOPE_AGENT);
            bad |= (vv[s] >> 8) ^ expct;
          }
          if (__all(bad == 0)) break;
          __builtin_amdgcn_s_sleep(2);
        }
      }
      u64 mb = 0;
#pragma unroll
      for (int s = 0; s < 8; ++s) mb |= (u64)(vv[s] & 0xFFu) << (8 * s);
      *(u64*)&MB[n][8 * w] = mb;
    }
    __syncthreads();  // bar1: MB complete (prev-iter MAC reads fenced by bar2)

    float SA = 0.f;
    if (expct) {
      // own row's 512 spike bits: 64 bytes -> 16 VGPRs
      const uint4* bq = (const uint4*)&MB[n][0];
      const uint4 q0 = bq[0], q1 = bq[1], q2 = bq[2], q3 = bq[3];
      const u32 bw[16] = { q0.x, q0.y, q0.z, q0.w, q1.x, q1.y, q1.z, q1.w,
                           q2.x, q2.y, q2.z, q2.w, q3.x, q3.y, q3.z, q3.w };
      float aA = 0.f, aB = 0.f;
      // BLAS-faithful: ascending k, chunk split at 384, merged by one fadd.
      // Per k: bfe_i32 (0/-1 mask) + and with uniform weight + fadd.
#pragma unroll
      for (int kb = 0; kb < 12; ++kb) {
        const u32 word = bw[kb];
#pragma unroll
        for (int t = 0; t < 32; ++t) {
          const int m = (int)(word << (31 - t)) >> 31;            // 0 / -1
          const float ws =
              __int_as_float(m & __float_as_int(Wrow[kb * 32 + t]));
          aA = __fadd_rn(aA, ws);
        }
      }
#pragma unroll
      for (int kb = 12; kb < 16; ++kb) {
        const u32 word = bw[kb];
#pragma unroll
        for (int t = 0; t < 32; ++t) {
          const int m = (int)(word << (31 - t)) >> 31;
          const float ws =
              __int_as_float(m & __float_as_int(Wrow[kb * 32 + t]));
          aB = __fadd_rn(aB, ws);
        }
      }
      SA = __fadd_rn(aA, aB);
    }

    // epilogue (single-rounded, identical op sequence to r10..r14)
    const float cur = isFF ? __fadd_rn(SA, coC)
                           : __fadd_rn(__fadd_rn(xw, SA), coC);
    syn = __fadd_rn(__fmul_rn(coA, syn), cur);
    mem = __fsub_rn(__fadd_rn(__fmul_rn(coB, mem), syn), spk);
    spk = (mem > 1.0f) ? 1.0f : 0.0f;
    SP[n][w] = (u8)(spk != 0.f);

    __syncthreads();  // bar2: SP complete; also fences MB reuse next iter

    if (w == 0) {
      const u64 sv  = *(const u64*)&SP[n][0];
      const u32 lo4 = ((u32)sv         * 0x01020408u) >> 24;  // bits w=0..3
      const u32 hi4 = ((u32)(sv >> 32) * 0x01020408u) >> 24;  // bits w=4..7
      const u32 mask = lo4 | (hi4 << 4);
      if (!isFF) {
        __hip_atomic_store(ring32 + ((u64)i * 64 + cb) * 128 + gn,
                           ((u32)(i + 1) << 8) | mask,
                           __ATOMIC_RELAXED, __HIP_MEMORY_SCOPE_AGENT);
      } else {
        spkb8[((u64)i * 64 + cb) * 128 + gn] = (u8)mask;
      }
    }
  }
}

// ---------------------------------------------------------------------------
// k_c3: spk_f history (bytes, c8-major) @ W_mu/W_lv readout, + bias.
// ---------------------------------------------------------------------------
__global__ __launch_bounds__(256) void k_c3(
    const u8* __restrict__ spkb8, const float* __restrict__ WT,
    const float* __restrict__ bmu, const float* __restrict__ blv,
    float* __restrict__ c3)
{
  __shared__ __align__(8) u8 Bc[64][40];  // [c8][n-local 32, pad 40]
  const int tid   = threadIdx.x;
  const int rows0 = blockIdx.x * 32;
  const int t     = rows0 >> 7;
  const int n0    = rows0 & 127;

  {
    const int c8 = tid >> 2, g = tid & 3;
    const u64 vv = *(const u64*)(spkb8 + ((u64)t * 64 + c8) * 128 + n0 + 8 * g);
    *(u64*)&Bc[c8][8 * g] = vv;
  }
  __syncthreads();

  const int j  = tid & 127;
  const int rh = tid >> 7;
  const float bias = (j < 64) ? bmu[j] : blv[j - 64];

  float accA[16], accB[16];
#pragma unroll
  for (int r = 0; r < 16; ++r) { accA[r] = 0.f; accB[r] = 0.f; }

  for (int m = 0; m < 48; ++m) {   // k = 8m+kk < 384
    u32 w32[4];
#pragma unroll
    for (int q = 0; q < 4; ++q) w32[q] = *(const u32*)&Bc[m][rh * 16 + 4 * q];
    const float* wpp = WT + (m * 8) * 128 + j;
#pragma unroll
    for (int kk = 0; kk < 8; ++kk) {
      const float wvv = wpp[kk * 128];
#pragma unroll
      for (int r = 0; r < 16; ++r) {
        const float b = (float)((w32[r >> 2] >> (((r & 3) << 3) + kk)) & 1u);
        accA[r] = __builtin_fmaf(b, wvv, accA[r]);
      }
    }
  }
  for (int m = 48; m < 64; ++m) {  // k >= 384
    u32 w32[4];
#pragma unroll
    for (int q = 0; q < 4; ++q) w32[q] = *(const u32*)&Bc[m][rh * 16 + 4 * q];
    const float* wpp = WT + (m * 8) * 128 + j;
#pragma unroll
    for (int kk = 0; kk < 8; ++kk) {
      const float wvv = wpp[kk * 128];
#pragma unroll
      for (int r = 0; r < 16; ++r) {
        const float b = (float)((w32[r >> 2] >> (((r & 3) << 3) + kk)) & 1u);
        accB[r] = __builtin_fmaf(b, wvv, accB[r]);
      }
    }
  }

#pragma unroll
  for (int r = 0; r < 16; ++r)
    c3[(u64)(rows0 + rh * 16 + r) * 128 + j] =
        __fadd_rn(__fadd_rn(accA[r], accB[r]), bias);
}

// ---------------------------------------------------------------------------
__global__ __launch_bounds__(256) void k_scan(
    const float* __restrict__ c3,
    const float* __restrict__ beta_mu, const float* __restrict__ beta_lv,
    float* __restrict__ Mem)
{
  const int tid = blockIdx.x * 256 + threadIdx.x;
  const int n = tid >> 7, ap = tid & 127;
  const float beta = (ap < 64) ? beta_mu[ap] : beta_lv[ap - 64];
  const float* src = c3 + n * 128 + ap;
  float* dst = Mem + n * 128 + ap;
  float mem = 0.0f;
  for (int t = 0; t < 512; ++t) {
    mem = __fadd_rn(__fmul_rn(beta, mem), src[(u64)t * 16384]);
    dst[(u64)t * 16384] = mem;
  }
}

// ---------------------------------------------------------------------------
__global__ __launch_bounds__(256) void k_out(
    const float* __restrict__ Mem,
    const float* __restrict__ Wmu_out, const float* __restrict__ Wlv_out,
    float* __restrict__ out)
{
  const int tid = blockIdx.x * 256 + threadIdx.x;
  const int a = tid & 7;
  const int n = (tid >> 3) & 127;
  const int t = (tid >> 10) & 255;
  const int kind = tid >> 18;
  const float* wv = ((kind == 0) ? Wmu_out : Wlv_out) + a * 64;
  const float* s0 = Mem + ((u64)(2 * t) * 128 + n) * 128 + kind * 64;
  const float* s1 = Mem + ((u64)(2 * t + 1) * 128 + n) * 128 + kind * 64;
  float mu0 = 0.0f, mu1 = 0.0f;
#pragma unroll 8
  for (int q = 0; q < 64; ++q) mu0 = __builtin_fmaf(s0[q], wv[q], mu0);
#pragma unroll 8
  for (int q = 0; q < 64; ++q) mu1 = __builtin_fmaf(s1[q], wv[q], mu1);
  out[tid] = __fmul_rn(__fadd_rn(mu0, mu1), 0.5f);
}

// ---------------------------------------------------------------------------
extern "C" void kernel_launch(void* const* d_in, const int* in_sizes, int n_in,
                              void* d_out, int out_size, void* d_ws, size_t ws_size,
                              hipStream_t stream) {
  (void)in_sizes; (void)n_in; (void)out_size;
  if (ws_size < WS_NEED) return;

  const float* state     = (const float*)d_in[0];
  const float* target    = (const float*)d_in[1];
  const float* W_rec_in  = (const float*)d_in[2];
  const float* b_rec_in  = (const float*)d_in[3];
  const float* W_rec     = (const float*)d_in[4];
  const float* b_rec     = (const float*)d_in[5];
  const float* alpha_rec = (const float*)d_in[6];
  const float* beta_rec  = (const float*)d_in[7];
  const float* W_ff_in   = (const float*)d_in[8];
  const float* b_ff_in   = (const float*)d_in[9];
  const float* alpha_ff  = (const float*)d_in[10];
  const float* beta_ff   = (const float*)d_in[11];
  const float* W_mu_in   = (const float*)d_in[12];
  const float* b_mu_in   = (const float*)d_in[13];
  const float* beta_mu   = (const float*)d_in[14];
  const float* W_mu_out  = (const float*)d_in[15];
  const float* W_lv_in   = (const float*)d_in[16];
  const float* b_lv_in   = (const float*)d_in[17];
  const float* beta_lv   = (const float*)d_in[18];
  const float* W_lv_out  = (const float*)d_in[19];

  char* ws = (char*)d_ws;
  float* XWT   = (float*)(ws + XW_OFF);
  float* c3    = (float*)(ws + C3_OFF);
  float* Mem   = (float*)(ws + MEM_OFF);
  u32*   ring32= (u32*)  (ws + RINGN_OFF);
  u8*    spkb8 = (u8*)   (ws + SPKB_OFF);
  float* WT    = (float*)(ws + WT_OFF);
  float* WinT  = (float*)(ws + WINT_OFF);

  hipLaunchKernelGGL(k_prepT, dim3(512), dim3(256), 0, stream,
                     W_rec_in, W_mu_in, W_lv_in, WinT, WT);
  hipLaunchKernelGGL(k_xw, dim3(2048), dim3(256), 0, stream,
                     state, target, WinT, b_rec_in, XWT);
  hipLaunchKernelGGL(k_rec, dim3(256), dim3(512), 0, stream,
                     XWT, W_rec, W_ff_in,
                     alpha_rec, beta_rec, b_rec,
                     b_ff_in, alpha_ff, beta_ff, ring32, spkb8);
  hipLaunchKernelGGL(k_c3, dim3(2048), dim3(256), 0, stream,
                     spkb8, WT, b_mu_in, b_lv_in, c3);
  hipLaunchKernelGGL(k_scan, dim3(64), dim3(256), 0, stream,
                     c3, beta_mu, beta_lv, Mem);
  hipLaunchKernelGGL(k_out, dim3(2048), dim3(256), 0, stream,
                     Mem, W_mu_out, W_lv_out, (float*)d_out);
}

// Round 8
// 4546.455 us; speedup vs baseline: 1.8766x; 1.1334x over previous
//
#include <hip/hip_runtime.h>

// ---------------------------------------------------------------------------
// PolicyNetRSNNPB forward, MI355X/gfx950.  Round 17: r16 structure, two bugs
// fixed.
// r16 FAILED (absmax 3.3): MB was u32[2][16][36] storing one mask16 per u32
// slot, but the MAC read rows as dense 32-bit words -> consumed only half the
// row at wrong bit positions. FIX: MB is u16[2][16][32] (dense 64B row);
// uint4 reads then give bw[d] bit q = unit 32d+q, matching the ballot-store
// word mapping (word wx bit b = unit 16wx+b). Protocol itself re-derived
// sound (poll(s+2) success implies all readers of tag s+1 finished).
// Second fix: WL stride 516 dwords had bank base 4u mod 32 -> 4-way conflict
// on every b128 weight read (the dominant LDS stream). Restride to 514
// (bank step 2 -> 2-way = free) with float2 reads/writes (8B aligned,
// fusable to ds_read2_b64).
// Structure unchanged from r16: 256 blocks (128 rec + 128 ff) x 512 threads,
// block = 32 units x 16 rows, wave = 32 units x 2 rows; ZERO per-step
// barriers (staging rows wave-private, MB parity dbuf, poll-gated skew);
// 1 tagged mask16 word polled per thread (hot 32KB parity ring for rec,
// 8MB no-reuse hist for ff); per-wave ballot stores; memset-zeroed tags.
// Arithmetic FROZEN (numpy-fp32 emulation), BIT-EXACT to r10..r15: ascending
// k per accumulator, K split [0,384)+[384,512) merged by one fadd; bit=1 ->
// fadd(acc,w), bit=0 -> fadd(acc,+0); epilogue single-rounded identical.
// ---------------------------------------------------------------------------

typedef unsigned int       u32;
typedef unsigned short     u16;
typedef unsigned long long u64;
typedef unsigned char      u8;

#define TSTEPS 512
#define HIDDEN 512

// workspace layout (bytes).
//   [0,64Mi)      XW (dead after k_rec; c3 [0,32Mi) + Mem [32Mi,64Mi))
//   [64Mi,+32K)   ring32: 2-slot parity ring, tag16|mask16, hot
//   [65Mi,+8Mi)   hist32: tagged no-reuse rec-spike history (for ff)
//   [80Mi,+4Mi)   spkb16: ff spike mask16 history (for k_c3)
//   [104Mi..)     WT, WinT (unchanged)
#define XW_OFF    0ull
#define C3_OFF    0ull
#define MEM_OFF   33554432ull
#define RING_OFF  67108864ull
#define HIST_OFF  68157440ull
#define SPKB_OFF  83886080ull
#define WT_OFF    109051904ull
#define WINT_OFF  109314048ull
#define WS_NEED   (134742016ull + 4096ull)

#define WSTRIDE 514   // dwords; bank step 2 -> 2-way (free) on weight reads

// ---------------------------------------------------------------------------
__global__ __launch_bounds__(256) void k_prepT(
    const float* __restrict__ Win,
    const float* __restrict__ Wmu, const float* __restrict__ Wlv,
    float* __restrict__ WinT, float* __restrict__ WT)
{
  const int idx = blockIdx.x * 256 + threadIdx.x;
  if (idx < 65536) {
    const int k = idx >> 9, j = idx & 511;
    WinT[idx] = Win[j * 128 + k];
  } else {
    const int i2 = idx - 65536;
    const int k = i2 >> 7, j = i2 & 127;
    WT[i2] = (j < 64) ? Wmu[j * 512 + k] : Wlv[(j - 64) * 512 + k];
  }
}

// ---------------------------------------------------------------------------
// k_xw: XW[(t2*128 + n)*512 + j] row-major (k_rec lanes read coalesced 128B).
// ---------------------------------------------------------------------------
__global__ __launch_bounds__(256) void k_xw(
    const float* __restrict__ state, const float* __restrict__ target,
    const float* __restrict__ WinT, const float* __restrict__ b_in,
    float* __restrict__ XW)
{
  __shared__ float xs[16][129];
  const int tid  = threadIdx.x;
  const int row0 = blockIdx.x * 16;

  for (int e = tid; e < 2048; e += 256) {
    int r = e >> 7, k = e & 127;
    xs[r][k] = (k < 64) ? state[(row0 + r) * 64 + k]
                        : target[(row0 + r) * 64 + k - 64];
  }
  __syncthreads();

#pragma unroll
  for (int jh = 0; jh < 2; ++jh) {
    const int j = jh * 256 + tid;
    float acc[16];
#pragma unroll
    for (int r = 0; r < 16; ++r) acc[r] = 0.0f;
    for (int k = 0; k < 128; ++k) {
      const float wv = WinT[k * 512 + j];
#pragma unroll
      for (int r = 0; r < 16; ++r)
        acc[r] = __builtin_fmaf(xs[r][k], wv, acc[r]);
    }
    const float b = b_in[j];
#pragma unroll
    for (int r = 0; r < 16; ++r)
      XW[(u64)(row0 + r) * 512 + j] = __fadd_rn(acc[r], b);
  }
}

// ---------------------------------------------------------------------------
// k_rec: grid 256 x 512 threads (8 waves, 2/SIMD, forced 1 block/CU via LDS).
// blockIdx < 128: REC; >= 128: FF. Block (layer, rg 0..7, c 0..15):
// units jj = 32c + (lane&31), rows g = 16rg + 2*wave + (lane>>5).
// Per step per wave (NO barriers): poll own mask16 word (tagged) -> u16 LDS
// write (wave-private row) -> 4x uint4 bit reads -> MAC (float2 weight
// stream, sbfe+and+fadd) -> epilogue -> ballot -> lanes 0-7 store ring/hist.
// ---------------------------------------------------------------------------
__global__ __launch_bounds__(512, 2) void k_rec(
    const float* __restrict__ XW,
    const float* __restrict__ Wrec, const float* __restrict__ Wff,
    const float* __restrict__ alpha_rec, const float* __restrict__ beta_rec,
    const float* __restrict__ b_rec,
    const float* __restrict__ b_ff, const float* __restrict__ alpha_ff,
    const float* __restrict__ beta_ff,
    u32* __restrict__ ring32, u32* __restrict__ hist32,
    u16* __restrict__ spkb16)
{
  __shared__ __align__(16) float WL[32 * WSTRIDE];  // 65792 B  weight tile
  __shared__ __align__(16) u16 MB[2][16][32];       //  2048 B  masks (dense!)
  __shared__ float padlds[3584];                    // 14336 B -> 82176 total:
                                                    // forces 1 block/CU.

  const int tid  = threadIdx.x;
  const int w    = tid >> 6;            // wave 0..7
  const int l    = tid & 63;            // lane
  const bool isFF = (blockIdx.x >= 128);
  const int bb   = blockIdx.x & 127;
  const int rg   = bb >> 4;             // row group 0..7
  const int c    = bb & 15;             // unit chunk 0..15
  const int u    = l & 31;              // unit within chunk
  const int rp   = l >> 5;              // row within wave pair
  const int rl   = 2 * w + rp;          // local row 0..15
  const int g    = 16 * rg + rl;        // global batch row 0..127
  const int jj   = 32 * c + u;          // hidden unit
  const int widx = l & 31;              // polled word index 0..31

  // stage weight tile: WL[u][k], stride 514 dwords, float2 granularity
  {
    const float* Wsrc = isFF ? Wff : Wrec;
    for (int it = tid; it < 8192; it += 512) {
      const int uu = it >> 8, m2 = (it & 255) * 2;
      *(float2*)(WL + uu * WSTRIDE + m2) =
          *(const float2*)(Wsrc + (u64)(32 * c + uu) * 512 + m2);
    }
  }

  const float coA = isFF ? alpha_ff[jj] : alpha_rec[jj];
  const float coB = isFF ? beta_ff[jj]  : beta_rec[jj];
  const float coC = isFF ? b_ff[jj]     : b_rec[jj];

  // keep the co-residency pad alive (never read back; one-time cost)
  ((volatile float*)padlds)[tid] = coC;

  const float* WLrow = WL + u * WSTRIDE;

  float syn = 0.f, mem = 0.f, spk = 0.f, xw = 0.f;

  __syncthreads();  // weights + pad ready (the ONLY barrier)

#pragma unroll 1
  for (int s = 0; s < TSTEPS; ++s) {
    const bool doMac = isFF || (s > 0);
    const int p = isFF ? (s & 1) : ((s - 1) & 1);   // MB parity slot

    if (doMac) {
      // ---- poll ONE tagged word (own row g, word widx) ----
      u32 v;
      if (!isFF) {
        const u32 expct = (u32)s;                   // stored at end of s-1
        const u32* src = ring32 + p * 4096 + g * 32 + widx;
        v = __hip_atomic_load(src, __ATOMIC_RELAXED, __HIP_MEMORY_SCOPE_AGENT);
        while ((v >> 16) != expct) {
          __builtin_amdgcn_s_sleep(1);
          v = __hip_atomic_load(src, __ATOMIC_RELAXED, __HIP_MEMORY_SCOPE_AGENT);
        }
      } else {
        const u32 expct = (u32)(s + 1);             // rec stores hist[s] tag s+1
        const u32* src = hist32 + (u64)s * 4096 + g * 32 + widx;
        v = __hip_atomic_load(src, __ATOMIC_RELAXED, __HIP_MEMORY_SCOPE_AGENT);
        while ((v >> 16) != expct) {
          __builtin_amdgcn_s_sleep(1);
          v = __hip_atomic_load(src, __ATOMIC_RELAXED, __HIP_MEMORY_SCOPE_AGENT);
        }
      }
      MB[p][rl][widx] = (u16)v;   // dense u16; wave-private row, no barrier
    }

    if (!isFF && !(s & 1))             // x reused across REPEAT=2
      xw = XW[((u64)(s >> 1) * 128 + g) * 512 + jj];

    float SA = 0.f;
    if (doMac) {
      // own row's 512 spike bits (written by own wave's lanes; dense 64B)
      const uint4* bq = (const uint4*)&MB[p][rl][0];
      const uint4 q0 = bq[0], q1 = bq[1], q2 = bq[2], q3 = bq[3];
      const u32 bw[16] = { q0.x, q0.y, q0.z, q0.w, q1.x, q1.y, q1.z, q1.w,
                           q2.x, q2.y, q2.z, q2.w, q3.x, q3.y, q3.z, q3.w };
      float aA = 0.f, aB = 0.f;
      // BLAS-faithful: ascending k, split at k=384 (d=12), one merge fadd.
      // Per k: sbfe (0/-1) + and + fadd = 3 VALU.
#pragma unroll
      for (int d = 0; d < 12; ++d) {
        const int word = (int)bw[d];
#pragma unroll
        for (int k4 = 0; k4 < 32; k4 += 4) {
          const float2 wa = *(const float2*)(WLrow + d * 32 + k4);
          const float2 wb = *(const float2*)(WLrow + d * 32 + k4 + 2);
          aA = __fadd_rn(aA, __int_as_float(
              __builtin_amdgcn_sbfe(word, k4 + 0, 1) & __float_as_int(wa.x)));
          aA = __fadd_rn(aA, __int_as_float(
              __builtin_amdgcn_sbfe(word, k4 + 1, 1) & __float_as_int(wa.y)));
          aA = __fadd_rn(aA, __int_as_float(
              __builtin_amdgcn_sbfe(word, k4 + 2, 1) & __float_as_int(wb.x)));
          aA = __fadd_rn(aA, __int_as_float(
              __builtin_amdgcn_sbfe(word, k4 + 3, 1) & __float_as_int(wb.y)));
        }
      }
#pragma unroll
      for (int d = 12; d < 16; ++d) {
        const int word = (int)bw[d];
#pragma unroll
        for (int k4 = 0; k4 < 32; k4 += 4) {
          const float2 wa = *(const float2*)(WLrow + d * 32 + k4);
          const float2 wb = *(const float2*)(WLrow + d * 32 + k4 + 2);
          aB = __fadd_rn(aB, __int_as_float(
              __builtin_amdgcn_sbfe(word, k4 + 0, 1) & __float_as_int(wa.x)));
          aB = __fadd_rn(aB, __int_as_float(
              __builtin_amdgcn_sbfe(word, k4 + 1, 1) & __float_as_int(wa.y)));
          aB = __fadd_rn(aB, __int_as_float(
              __builtin_amdgcn_sbfe(word, k4 + 2, 1) & __float_as_int(wb.x)));
          aB = __fadd_rn(aB, __int_as_float(
              __builtin_amdgcn_sbfe(word, k4 + 3, 1) & __float_as_int(wb.y)));
        }
      }
      SA = __fadd_rn(aA, aB);
    }

    // epilogue (single-rounded, identical op sequence to r10..r16)
    const float cur = isFF ? __fadd_rn(SA, coC)
                           : __fadd_rn(__fadd_rn(xw, SA), coC);
    syn = __fadd_rn(__fmul_rn(coA, syn), cur);
    mem = __fsub_rn(__fadd_rn(__fmul_rn(coB, mem), syn), spk);
    spk = (mem > 1.0f) ? 1.0f : 0.0f;

    // per-wave ballot store: bits 0..31 = units of row 2w, 32..63 row 2w+1
    const u64 B = __ballot(spk != 0.f);
    if (!isFF) {
      if (l < 4) {
        const u32 word = (u32)(B >> (16 * l)) & 0xFFFFu;
        const int gs = 16 * rg + 2 * w + (l >> 1);
        const int wx = 2 * c + (l & 1);
        __hip_atomic_store(ring32 + (s & 1) * 4096 + gs * 32 + wx,
                           ((u32)(s + 1) << 16) | word,
                           __ATOMIC_RELAXED, __HIP_MEMORY_SCOPE_AGENT);
      } else if (l < 8) {
        const int l2 = l - 4;
        const u32 word = (u32)(B >> (16 * l2)) & 0xFFFFu;
        const int gs = 16 * rg + 2 * w + (l2 >> 1);
        const int wx = 2 * c + (l2 & 1);
        __hip_atomic_store(hist32 + (u64)s * 4096 + gs * 32 + wx,
                           ((u32)(s + 1) << 16) | word,
                           __ATOMIC_RELAXED, __HIP_MEMORY_SCOPE_AGENT);
      }
    } else {
      if (l < 4) {
        const u32 word = (u32)(B >> (16 * l)) & 0xFFFFu;
        const int gs = 16 * rg + 2 * w + (l >> 1);
        const int wx = 2 * c + (l & 1);
        spkb16[(u64)s * 4096 + gs * 32 + wx] = (u16)word;
      }
    }
    // no end-of-step barrier: staging rows are wave-private; parity dbuf +
    // poll gating bound skew (reaching store(s) requires poll(s) success,
    // which requires every same-rowgroup wave finished poll(s-1)).
  }
}

// ---------------------------------------------------------------------------
// k_c3: ff spike history (mask16 words) @ W_mu/W_lv readout, + bias.
// Same ascending-k FMA order (k = 16*wi + kk), split at wi=24 (k=384).
// ---------------------------------------------------------------------------
__global__ __launch_bounds__(256) void k_c3(
    const u16* __restrict__ spkb16, const float* __restrict__ WT,
    const float* __restrict__ bmu, const float* __restrict__ blv,
    float* __restrict__ c3)
{
  __shared__ __align__(8) u16 Bc[32][36];  // [row-local][32 w16, pad 36]
  const int tid   = threadIdx.x;
  const int rows0 = blockIdx.x * 32;

  {
    const int r = tid >> 3, gq = tid & 7;   // 32 rows x 8B
    const u64 vv = *(const u64*)(spkb16 + (u64)(rows0 + r) * 32 + 4 * gq);
    *(u64*)&Bc[r][4 * gq] = vv;
  }
  __syncthreads();

  const int j  = tid & 127;
  const int rh = tid >> 7;
  const float bias = (j < 64) ? bmu[j] : blv[j - 64];

  float accA[16], accB[16];
#pragma unroll
  for (int r = 0; r < 16; ++r) { accA[r] = 0.f; accB[r] = 0.f; }

  for (int wi = 0; wi < 24; ++wi) {   // k = 16*wi + kk < 384
    u16 wrow[16];
#pragma unroll
    for (int r = 0; r < 16; ++r) wrow[r] = Bc[rh * 16 + r][wi];
    const float* wpp = WT + (wi * 16) * 128 + j;
#pragma unroll
    for (int kk = 0; kk < 16; ++kk) {
      const float wvv = wpp[kk * 128];
#pragma unroll
      for (int r = 0; r < 16; ++r) {
        const float b = (float)((wrow[r] >> kk) & 1u);
        accA[r] = __builtin_fmaf(b, wvv, accA[r]);
      }
    }
  }
  for (int wi = 24; wi < 32; ++wi) {  // k >= 384
    u16 wrow[16];
#pragma unroll
    for (int r = 0; r < 16; ++r) wrow[r] = Bc[rh * 16 + r][wi];
    const float* wpp = WT + (wi * 16) * 128 + j;
#pragma unroll
    for (int kk = 0; kk < 16; ++kk) {
      const float wvv = wpp[kk * 128];
#pragma unroll
      for (int r = 0; r < 16; ++r) {
        const float b = (float)((wrow[r] >> kk) & 1u);
        accB[r] = __builtin_fmaf(b, wvv, accB[r]);
      }
    }
  }

#pragma unroll
  for (int r = 0; r < 16; ++r)
    c3[(u64)(rows0 + rh * 16 + r) * 128 + j] =
        __fadd_rn(__fadd_rn(accA[r], accB[r]), bias);
}

// ---------------------------------------------------------------------------
__global__ __launch_bounds__(256) void k_scan(
    const float* __restrict__ c3,
    const float* __restrict__ beta_mu, const float* __restrict__ beta_lv,
    float* __restrict__ Mem)
{
  const int tid = blockIdx.x * 256 + threadIdx.x;
  const int n = tid >> 7, ap = tid & 127;
  const float beta = (ap < 64) ? beta_mu[ap] : beta_lv[ap - 64];
  const float* src = c3 + n * 128 + ap;
  float* dst = Mem + n * 128 + ap;
  float mem = 0.0f;
  for (int t = 0; t < 512; ++t) {
    mem = __fadd_rn(__fmul_rn(beta, mem), src[(u64)t * 16384]);
    dst[(u64)t * 16384] = mem;
  }
}

// ---------------------------------------------------------------------------
__global__ __launch_bounds__(256) void k_out(
    const float* __restrict__ Mem,
    const float* __restrict__ Wmu_out, const float* __restrict__ Wlv_out,
    float* __restrict__ out)
{
  const int tid = blockIdx.x * 256 + threadIdx.x;
  const int a = tid & 7;
  const int n = (tid >> 3) & 127;
  const int t = (tid >> 10) & 255;
  const int kind = tid >> 18;
  const float* wv = ((kind == 0) ? Wmu_out : Wlv_out) + a * 64;
  const float* s0 = Mem + ((u64)(2 * t) * 128 + n) * 128 + kind * 64;
  const float* s1 = Mem + ((u64)(2 * t + 1) * 128 + n) * 128 + kind * 64;
  float mu0 = 0.0f, mu1 = 0.0f;
#pragma unroll 8
  for (int q = 0; q < 64; ++q) mu0 = __builtin_fmaf(s0[q], wv[q], mu0);
#pragma unroll 8
  for (int q = 0; q < 64; ++q) mu1 = __builtin_fmaf(s1[q], wv[q], mu1);
  out[tid] = __fmul_rn(__fadd_rn(mu0, mu1), 0.5f);
}

// ---------------------------------------------------------------------------
extern "C" void kernel_launch(void* const* d_in, const int* in_sizes, int n_in,
                              void* d_out, int out_size, void* d_ws, size_t ws_size,
                              hipStream_t stream) {
  (void)in_sizes; (void)n_in; (void)out_size;
  if (ws_size < WS_NEED) return;

  const float* state     = (const float*)d_in[0];
  const float* target    = (const float*)d_in[1];
  const float* W_rec_in  = (const float*)d_in[2];
  const float* b_rec_in  = (const float*)d_in[3];
  const float* W_rec     = (const float*)d_in[4];
  const float* b_rec     = (const float*)d_in[5];
  const float* alpha_rec = (const float*)d_in[6];
  const float* beta_rec  = (const float*)d_in[7];
  const float* W_ff_in   = (const float*)d_in[8];
  const float* b_ff_in   = (const float*)d_in[9];
  const float* alpha_ff  = (const float*)d_in[10];
  const float* beta_ff   = (const float*)d_in[11];
  const float* W_mu_in   = (const float*)d_in[12];
  const float* b_mu_in   = (const float*)d_in[13];
  const float* beta_mu   = (const float*)d_in[14];
  const float* W_mu_out  = (const float*)d_in[15];
  const float* W_lv_in   = (const float*)d_in[16];
  const float* b_lv_in   = (const float*)d_in[17];
  const float* beta_lv   = (const float*)d_in[18];
  const float* W_lv_out  = (const float*)d_in[19];

  char* ws = (char*)d_ws;
  float* XW    = (float*)(ws + XW_OFF);
  float* c3    = (float*)(ws + C3_OFF);
  float* Mem   = (float*)(ws + MEM_OFF);
  u32*   ring32= (u32*)  (ws + RING_OFF);
  u32*   hist32= (u32*)  (ws + HIST_OFF);
  u16*   spkb16= (u16*)  (ws + SPKB_OFF);
  float* WT    = (float*)(ws + WT_OFF);
  float* WinT  = (float*)(ws + WINT_OFF);

  // zero the tagged regions so tags (>=1) can never false-match poison
  hipMemsetAsync(ws + RING_OFF, 0, 32768, stream);
  hipMemsetAsync(ws + HIST_OFF, 0, 8388608, stream);

  hipLaunchKernelGGL(k_prepT, dim3(512), dim3(256), 0, stream,
                     W_rec_in, W_mu_in, W_lv_in, WinT, WT);
  hipLaunchKernelGGL(k_xw, dim3(2048), dim3(256), 0, stream,
                     state, target, WinT, b_rec_in, XW);
  hipLaunchKernelGGL(k_rec, dim3(256), dim3(512), 0, stream,
                     XW, W_rec, W_ff_in,
                     alpha_rec, beta_rec, b_rec,
                     b_ff_in, alpha_ff, beta_ff, ring32, hist32, spkb16);
  hipLaunchKernelGGL(k_c3, dim3(2048), dim3(256), 0, stream,
                     spkb16, WT, b_mu_in, b_lv_in, c3);
  hipLaunchKernelGGL(k_scan, dim3(64), dim3(256), 0, stream,
                     c3, beta_mu, beta_lv, Mem);
  hipLaunchKernelGGL(k_out, dim3(2048), dim3(256), 0, stream,
                     Mem, W_mu_out, W_lv_out, (float*)d_out);
}

// Round 9
// 3927.240 us; speedup vs baseline: 2.1725x; 1.1577x over previous
//
#include <hip/hip_runtime.h>

// ---------------------------------------------------------------------------
// PolicyNetRSNNPB forward, MI355X/gfx950.  Round 18: mixed-role CUs.
// r17 passed (wall 4546, k_rec 4210 us = 8.2 us/step). Protocol + MAC proven;
// remaining wall is exchange latency with NOTHING to hide it: blocks are
// role-homogeneous, so all 8 waves of a rec CU stall together at each clique
// exchange (r10's mixed-role shell had ~2.1 us overhead for exactly this
// reason). THIS ROUND: every block = 4 rec waves + 4 ff waves over the same
// (rg: 8 rows, c: 32 units) tile; 256 blocks = 16 rowgroups x 16 chunks.
// Wave w -> SIMD w&3, so each SIMD hosts 1 rec + 1 ff wave: when rec polls
// its clique, ff MACs (ff consumes the NO-REUSE hist, always available,
// never gates rec); when ff polls, rec MACs. rec waves run at s_setprio(1)
// (role-diverse schedule -> priority pays, T5) so clique stores issue ASAP.
//   * Both weight tiles in LDS: WR+WF = 2 x 65792 B, + MB 1 KB = 132608 B
//     -> forces 1 block/CU (precedent: r11 ran 132096 B).
//   * MB loses the parity dim: staging rows are wave-private and written-
//     then-read within one iteration -> wave program order suffices.
//   * Protocol unchanged from r17 (verified): 1 tagged mask16 word/thread
//     poll; hot 32KB parity ring within 16-block cliques (same rg); tagged
//     no-reuse hist (8MB) rec->ff; per-wave ballot stores; memset-zeroed
//     tags; ZERO per-step barriers. Slot-reuse induction identical (clique
//     membership unchanged).
// Arithmetic FROZEN (numpy-fp32 emulation), BIT-EXACT to r10..r17: ascending
// k per accumulator, K split [0,384)+[384,512) merged by one fadd; bit=1 ->
// fadd(acc,w), bit=0 -> fadd(acc,+0); epilogue single-rounded identical.
// k_prepT/k_xw/k_c3/k_scan/k_out unchanged from r17.
// ---------------------------------------------------------------------------

typedef unsigned int       u32;
typedef unsigned short     u16;
typedef unsigned long long u64;
typedef unsigned char      u8;

#define TSTEPS 512
#define HIDDEN 512

// workspace layout (bytes).
//   [0,64Mi)      XW (dead after k_rec; c3 [0,32Mi) + Mem [32Mi,64Mi))
//   [64Mi,+32K)   ring32: 2-slot parity ring, tag16|mask16, hot
//   [65Mi,+8Mi)   hist32: tagged no-reuse rec-spike history (for ff)
//   [80Mi,+4Mi)   spkb16: ff spike mask16 history (for k_c3)
//   [104Mi..)     WT, WinT (unchanged)
#define XW_OFF    0ull
#define C3_OFF    0ull
#define MEM_OFF   33554432ull
#define RING_OFF  67108864ull
#define HIST_OFF  68157440ull
#define SPKB_OFF  83886080ull
#define WT_OFF    109051904ull
#define WINT_OFF  109314048ull
#define WS_NEED   (134742016ull + 4096ull)

#define WSTRIDE 514   // dwords; bank step 2 -> 2-way (free) on weight reads

// ---------------------------------------------------------------------------
__global__ __launch_bounds__(256) void k_prepT(
    const float* __restrict__ Win,
    const float* __restrict__ Wmu, const float* __restrict__ Wlv,
    float* __restrict__ WinT, float* __restrict__ WT)
{
  const int idx = blockIdx.x * 256 + threadIdx.x;
  if (idx < 65536) {
    const int k = idx >> 9, j = idx & 511;
    WinT[idx] = Win[j * 128 + k];
  } else {
    const int i2 = idx - 65536;
    const int k = i2 >> 7, j = i2 & 127;
    WT[i2] = (j < 64) ? Wmu[j * 512 + k] : Wlv[(j - 64) * 512 + k];
  }
}

// ---------------------------------------------------------------------------
// k_xw: XW[(t2*128 + n)*512 + j] row-major (k_rec lanes read coalesced 128B).
// ---------------------------------------------------------------------------
__global__ __launch_bounds__(256) void k_xw(
    const float* __restrict__ state, const float* __restrict__ target,
    const float* __restrict__ WinT, const float* __restrict__ b_in,
    float* __restrict__ XW)
{
  __shared__ float xs[16][129];
  const int tid  = threadIdx.x;
  const int row0 = blockIdx.x * 16;

  for (int e = tid; e < 2048; e += 256) {
    int r = e >> 7, k = e & 127;
    xs[r][k] = (k < 64) ? state[(row0 + r) * 64 + k]
                        : target[(row0 + r) * 64 + k - 64];
  }
  __syncthreads();

#pragma unroll
  for (int jh = 0; jh < 2; ++jh) {
    const int j = jh * 256 + tid;
    float acc[16];
#pragma unroll
    for (int r = 0; r < 16; ++r) acc[r] = 0.0f;
    for (int k = 0; k < 128; ++k) {
      const float wv = WinT[k * 512 + j];
#pragma unroll
      for (int r = 0; r < 16; ++r)
        acc[r] = __builtin_fmaf(xs[r][k], wv, acc[r]);
    }
    const float b = b_in[j];
#pragma unroll
    for (int r = 0; r < 16; ++r)
      XW[(u64)(row0 + r) * 512 + j] = __fadd_rn(acc[r], b);
  }
}

// ---------------------------------------------------------------------------
// k_rec: grid 256 x 512 threads; block = (rg 0..15: 8 rows, c 0..15: 32
// units); waves 0-3 rec, waves 4-7 ff (1 rec + 1 ff per SIMD).
// Per wave per step (NO barriers): poll own tagged mask16 word -> u16 LDS
// write (wave-private row) -> uint4 bit reads -> MAC (float2 weight stream,
// sbfe+and+fadd, 3 VALU/MAC) -> epilogue -> ballot -> lanes 0-7 store.
// ---------------------------------------------------------------------------
__global__ __launch_bounds__(512, 2) void k_rec(
    const float* __restrict__ XW,
    const float* __restrict__ Wrec, const float* __restrict__ Wff,
    const float* __restrict__ alpha_rec, const float* __restrict__ beta_rec,
    const float* __restrict__ b_rec,
    const float* __restrict__ b_ff, const float* __restrict__ alpha_ff,
    const float* __restrict__ beta_ff,
    u32* __restrict__ ring32, u32* __restrict__ hist32,
    u16* __restrict__ spkb16)
{
  __shared__ __align__(16) float WR[32 * WSTRIDE];  // 65792 B
  __shared__ __align__(16) float WF[32 * WSTRIDE];  // 65792 B
  __shared__ __align__(16) u16 MBr[8][32];          //   512 B
  __shared__ __align__(16) u16 MBf[8][32];          //   512 B -> 132608 total
                                                    // (forces 1 block/CU)

  const int tid  = threadIdx.x;
  const int w    = tid >> 6;            // wave 0..7
  const int l    = tid & 63;            // lane
  const bool isFF = (w >= 4);
  const int wl   = w & 3;               // wave within role 0..3
  const int rg   = blockIdx.x >> 4;     // row group 0..15 (8 rows each)
  const int c    = blockIdx.x & 15;     // unit chunk 0..15 (32 units)
  const int u    = l & 31;              // unit within chunk
  const int rp   = l >> 5;              // row within wave pair
  const int rl   = 2 * wl + rp;         // local row 0..7
  const int g    = 8 * rg + rl;         // global batch row 0..127
  const int jj   = 32 * c + u;          // hidden unit
  const int widx = l & 31;              // polled word index 0..31

  // stage BOTH weight tiles: stride 514 dwords, float2 granularity
  for (int it = tid; it < 8192; it += 512) {
    const int uu = it >> 8, m2 = (it & 255) * 2;
    *(float2*)(WR + uu * WSTRIDE + m2) =
        *(const float2*)(Wrec + (u64)(32 * c + uu) * 512 + m2);
    *(float2*)(WF + uu * WSTRIDE + m2) =
        *(const float2*)(Wff + (u64)(32 * c + uu) * 512 + m2);
  }

  const float coA = isFF ? alpha_ff[jj] : alpha_rec[jj];
  const float coB = isFF ? beta_ff[jj]  : beta_rec[jj];
  const float coC = isFF ? b_ff[jj]     : b_rec[jj];

  const float* WLrow = (isFF ? WF : WR) + u * WSTRIDE;
  u16* MBrow = (isFF ? MBf : MBr)[rl];

  float syn = 0.f, mem = 0.f, spk = 0.f, xw = 0.f;

  __syncthreads();  // weights ready (the ONLY barrier)

  if (!isFF) __builtin_amdgcn_s_setprio(1);  // rec clique = critical path

#pragma unroll 1
  for (int s = 0; s < TSTEPS; ++s) {
    const bool doMac = isFF || (s > 0);

    if (doMac) {
      // ---- poll ONE tagged word (own row g, word widx) ----
      u32 v;
      if (!isFF) {
        const u32 expct = (u32)s;                   // stored end of step s-1
        const u32* src = ring32 + ((s - 1) & 1) * 4096 + g * 32 + widx;
        v = __hip_atomic_load(src, __ATOMIC_RELAXED, __HIP_MEMORY_SCOPE_AGENT);
        while ((v >> 16) != expct) {
          __builtin_amdgcn_s_sleep(1);
          v = __hip_atomic_load(src, __ATOMIC_RELAXED, __HIP_MEMORY_SCOPE_AGENT);
        }
      } else {
        const u32 expct = (u32)(s + 1);             // rec stores hist[s] tag s+1
        const u32* src = hist32 + (u64)s * 4096 + g * 32 + widx;
        v = __hip_atomic_load(src, __ATOMIC_RELAXED, __HIP_MEMORY_SCOPE_AGENT);
        while ((v >> 16) != expct) {
          __builtin_amdgcn_s_sleep(1);
          v = __hip_atomic_load(src, __ATOMIC_RELAXED, __HIP_MEMORY_SCOPE_AGENT);
        }
      }
      MBrow[widx] = (u16)v;   // wave-private row; program order suffices
    }

    if (!isFF && !(s & 1))             // x reused across REPEAT=2
      xw = XW[((u64)(s >> 1) * 128 + g) * 512 + jj];

    float SA = 0.f;
    if (doMac) {
      // own row's 512 spike bits (written by own wave's lanes; dense 64B)
      const uint4* bq = (const uint4*)MBrow;
      const uint4 q0 = bq[0], q1 = bq[1], q2 = bq[2], q3 = bq[3];
      const u32 bw[16] = { q0.x, q0.y, q0.z, q0.w, q1.x, q1.y, q1.z, q1.w,
                           q2.x, q2.y, q2.z, q2.w, q3.x, q3.y, q3.z, q3.w };
      float aA = 0.f, aB = 0.f;
      // BLAS-faithful: ascending k, split at k=384 (d=12), one merge fadd.
      // Per k: sbfe (0/-1) + and + fadd = 3 VALU.
#pragma unroll
      for (int d = 0; d < 12; ++d) {
        const int word = (int)bw[d];
#pragma unroll
        for (int k4 = 0; k4 < 32; k4 += 4) {
          const float2 wa = *(const float2*)(WLrow + d * 32 + k4);
          const float2 wb = *(const float2*)(WLrow + d * 32 + k4 + 2);
          aA = __fadd_rn(aA, __int_as_float(
              __builtin_amdgcn_sbfe(word, k4 + 0, 1) & __float_as_int(wa.x)));
          aA = __fadd_rn(aA, __int_as_float(
              __builtin_amdgcn_sbfe(word, k4 + 1, 1) & __float_as_int(wa.y)));
          aA = __fadd_rn(aA, __int_as_float(
              __builtin_amdgcn_sbfe(word, k4 + 2, 1) & __float_as_int(wb.x)));
          aA = __fadd_rn(aA, __int_as_float(
              __builtin_amdgcn_sbfe(word, k4 + 3, 1) & __float_as_int(wb.y)));
        }
      }
#pragma unroll
      for (int d = 12; d < 16; ++d) {
        const int word = (int)bw[d];
#pragma unroll
        for (int k4 = 0; k4 < 32; k4 += 4) {
          const float2 wa = *(const float2*)(WLrow + d * 32 + k4);
          const float2 wb = *(const float2*)(WLrow + d * 32 + k4 + 2);
          aB = __fadd_rn(aB, __int_as_float(
              __builtin_amdgcn_sbfe(word, k4 + 0, 1) & __float_as_int(wa.x)));
          aB = __fadd_rn(aB, __int_as_float(
              __builtin_amdgcn_sbfe(word, k4 + 1, 1) & __float_as_int(wa.y)));
          aB = __fadd_rn(aB, __int_as_float(
              __builtin_amdgcn_sbfe(word, k4 + 2, 1) & __float_as_int(wb.x)));
          aB = __fadd_rn(aB, __int_as_float(
              __builtin_amdgcn_sbfe(word, k4 + 3, 1) & __float_as_int(wb.y)));
        }
      }
      SA = __fadd_rn(aA, aB);
    }

    // epilogue (single-rounded, identical op sequence to r10..r17)
    const float cur = isFF ? __fadd_rn(SA, coC)
                           : __fadd_rn(__fadd_rn(xw, SA), coC);
    syn = __fadd_rn(__fmul_rn(coA, syn), cur);
    mem = __fsub_rn(__fadd_rn(__fmul_rn(coB, mem), syn), spk);
    spk = (mem > 1.0f) ? 1.0f : 0.0f;

    // per-wave ballot store: bits 0..31 = row 2wl, bits 32..63 = row 2wl+1
    const u64 B = __ballot(spk != 0.f);
    const int rowbase = 8 * rg + 2 * wl;
    if (!isFF) {
      if (l < 4) {
        const u32 word = (u32)(B >> (16 * l)) & 0xFFFFu;
        const int gs = rowbase + (l >> 1);
        const int wx = 2 * c + (l & 1);
        __hip_atomic_store(ring32 + (s & 1) * 4096 + gs * 32 + wx,
                           ((u32)(s + 1) << 16) | word,
                           __ATOMIC_RELAXED, __HIP_MEMORY_SCOPE_AGENT);
      } else if (l < 8) {
        const int l2 = l - 4;
        const u32 word = (u32)(B >> (16 * l2)) & 0xFFFFu;
        const int gs = rowbase + (l2 >> 1);
        const int wx = 2 * c + (l2 & 1);
        __hip_atomic_store(hist32 + (u64)s * 4096 + gs * 32 + wx,
                           ((u32)(s + 1) << 16) | word,
                           __ATOMIC_RELAXED, __HIP_MEMORY_SCOPE_AGENT);
      }
    } else {
      if (l < 4) {
        const u32 word = (u32)(B >> (16 * l)) & 0xFFFFu;
        const int gs = rowbase + (l >> 1);
        const int wx = 2 * c + (l & 1);
        spkb16[(u64)s * 4096 + gs * 32 + wx] = (u16)word;
      }
    }
    // no end-of-step barrier: staging rows are wave-private; poll gating
    // bounds skew (reaching store(s) requires poll(s) success, which requires
    // every clique wave of this row finished reading step s-2's slot).
  }
}

// ---------------------------------------------------------------------------
// k_c3: ff spike history (mask16 words) @ W_mu/W_lv readout, + bias.
// Same ascending-k FMA order (k = 16*wi + kk), split at wi=24 (k=384).
// ---------------------------------------------------------------------------
__global__ __launch_bounds__(256) void k_c3(
    const u16* __restrict__ spkb16, const float* __restrict__ WT,
    const float* __restrict__ bmu, const float* __restrict__ blv,
    float* __restrict__ c3)
{
  __shared__ __align__(8) u16 Bc[32][36];  // [row-local][32 w16, pad 36]
  const int tid   = threadIdx.x;
  const int rows0 = blockIdx.x * 32;

  {
    const int r = tid >> 3, gq = tid & 7;   // 32 rows x 8B
    const u64 vv = *(const u64*)(spkb16 + (u64)(rows0 + r) * 32 + 4 * gq);
    *(u64*)&Bc[r][4 * gq] = vv;
  }
  __syncthreads();

  const int j  = tid & 127;
  const int rh = tid >> 7;
  const float bias = (j < 64) ? bmu[j] : blv[j - 64];

  float accA[16], accB[16];
#pragma unroll
  for (int r = 0; r < 16; ++r) { accA[r] = 0.f; accB[r] = 0.f; }

  for (int wi = 0; wi < 24; ++wi) {   // k = 16*wi + kk < 384
    u16 wrow[16];
#pragma unroll
    for (int r = 0; r < 16; ++r) wrow[r] = Bc[rh * 16 + r][wi];
    const float* wpp = WT + (wi * 16) * 128 + j;
#pragma unroll
    for (int kk = 0; kk < 16; ++kk) {
      const float wvv = wpp[kk * 128];
#pragma unroll
      for (int r = 0; r < 16; ++r) {
        const float b = (float)((wrow[r] >> kk) & 1u);
        accA[r] = __builtin_fmaf(b, wvv, accA[r]);
      }
    }
  }
  for (int wi = 24; wi < 32; ++wi) {  // k >= 384
    u16 wrow[16];
#pragma unroll
    for (int r = 0; r < 16; ++r) wrow[r] = Bc[rh * 16 + r][wi];
    const float* wpp = WT + (wi * 16) * 128 + j;
#pragma unroll
    for (int kk = 0; kk < 16; ++kk) {
      const float wvv = wpp[kk * 128];
#pragma unroll
      for (int r = 0; r < 16; ++r) {
        const float b = (float)((wrow[r] >> kk) & 1u);
        accB[r] = __builtin_fmaf(b, wvv, accB[r]);
      }
    }
  }

#pragma unroll
  for (int r = 0; r < 16; ++r)
    c3[(u64)(rows0 + rh * 16 + r) * 128 + j] =
        __fadd_rn(__fadd_rn(accA[r], accB[r]), bias);
}

// ---------------------------------------------------------------------------
__global__ __launch_bounds__(256) void k_scan(
    const float* __restrict__ c3,
    const float* __restrict__ beta_mu, const float* __restrict__ beta_lv,
    float* __restrict__ Mem)
{
  const int tid = blockIdx.x * 256 + threadIdx.x;
  const int n = tid >> 7, ap = tid & 127;
  const float beta = (ap < 64) ? beta_mu[ap] : beta_lv[ap - 64];
  const float* src = c3 + n * 128 + ap;
  float* dst = Mem + n * 128 + ap;
  float mem = 0.0f;
  for (int t = 0; t < 512; ++t) {
    mem = __fadd_rn(__fmul_rn(beta, mem), src[(u64)t * 16384]);
    dst[(u64)t * 16384] = mem;
  }
}

// ---------------------------------------------------------------------------
__global__ __launch_bounds__(256) void k_out(
    const float* __restrict__ Mem,
    const float* __restrict__ Wmu_out, const float* __restrict__ Wlv_out,
    float* __restrict__ out)
{
  const int tid = blockIdx.x * 256 + threadIdx.x;
  const int a = tid & 7;
  const int n = (tid >> 3) & 127;
  const int t = (tid >> 10) & 255;
  const int kind = tid >> 18;
  const float* wv = ((kind == 0) ? Wmu_out : Wlv_out) + a * 64;
  const float* s0 = Mem + ((u64)(2 * t) * 128 + n) * 128 + kind * 64;
  const float* s1 = Mem + ((u64)(2 * t + 1) * 128 + n) * 128 + kind * 64;
  float mu0 = 0.0f, mu1 = 0.0f;
#pragma unroll 8
  for (int q = 0; q < 64; ++q) mu0 = __builtin_fmaf(s0[q], wv[q], mu0);
#pragma unroll 8
  for (int q = 0; q < 64; ++q) mu1 = __builtin_fmaf(s1[q], wv[q], mu1);
  out[tid] = __fmul_rn(__fadd_rn(mu0, mu1), 0.5f);
}

// ---------------------------------------------------------------------------
extern "C" void kernel_launch(void* const* d_in, const int* in_sizes, int n_in,
                              void* d_out, int out_size, void* d_ws, size_t ws_size,
                              hipStream_t stream) {
  (void)in_sizes; (void)n_in; (void)out_size;
  if (ws_size < WS_NEED) return;

  const float* state     = (const float*)d_in[0];
  const float* target    = (const float*)d_in[1];
  const float* W_rec_in  = (const float*)d_in[2];
  const float* b_rec_in  = (const float*)d_in[3];
  const float* W_rec     = (const float*)d_in[4];
  const float* b_rec     = (const float*)d_in[5];
  const float* alpha_rec = (const float*)d_in[6];
  const float* beta_rec  = (const float*)d_in[7];
  const float* W_ff_in   = (const float*)d_in[8];
  const float* b_ff_in   = (const float*)d_in[9];
  const float* alpha_ff  = (const float*)d_in[10];
  const float* beta_ff   = (const float*)d_in[11];
  const float* W_mu_in   = (const float*)d_in[12];
  const float* b_mu_in   = (const float*)d_in[13];
  const float* beta_mu   = (const float*)d_in[14];
  const float* W_mu_out  = (const float*)d_in[15];
  const float* W_lv_in   = (const float*)d_in[16];
  const float* b_lv_in   = (const float*)d_in[17];
  const float* beta_lv   = (const float*)d_in[18];
  const float* W_lv_out  = (const float*)d_in[19];

  char* ws = (char*)d_ws;
  float* XW    = (float*)(ws + XW_OFF);
  float* c3    = (float*)(ws + C3_OFF);
  float* Mem   = (float*)(ws + MEM_OFF);
  u32*   ring32= (u32*)  (ws + RING_OFF);
  u32*   hist32= (u32*)  (ws + HIST_OFF);
  u16*   spkb16= (u16*)  (ws + SPKB_OFF);
  float* WT    = (float*)(ws + WT_OFF);
  float* WinT  = (float*)(ws + WINT_OFF);

  // zero the tagged regions so tags (>=1) can never false-match poison
  hipMemsetAsync(ws + RING_OFF, 0, 32768, stream);
  hipMemsetAsync(ws + HIST_OFF, 0, 8388608, stream);

  hipLaunchKernelGGL(k_prepT, dim3(512), dim3(256), 0, stream,
                     W_rec_in, W_mu_in, W_lv_in, WinT, WT);
  hipLaunchKernelGGL(k_xw, dim3(2048), dim3(256), 0, stream,
                     state, target, WinT, b_rec_in, XW);
  hipLaunchKernelGGL(k_rec, dim3(256), dim3(512), 0, stream,
                     XW, W_rec, W_ff_in,
                     alpha_rec, beta_rec, b_rec,
                     b_ff_in, alpha_ff, beta_ff, ring32, hist32, spkb16);
  hipLaunchKernelGGL(k_c3, dim3(2048), dim3(256), 0, stream,
                     spkb16, WT, b_mu_in, b_lv_in, c3);
  hipLaunchKernelGGL(k_scan, dim3(64), dim3(256), 0, stream,
                     c3, beta_mu, beta_lv, Mem);
  hipLaunchKernelGGL(k_out, dim3(2048), dim3(256), 0, stream,
                     Mem, W_mu_out, W_lv_out, (float*)d_out);
}